// Round 1
// baseline (386.531 us; speedup 1.0000x reference)
//
#include <hip/hip_runtime.h>
#include <hip/hip_bf16.h>

// Problem constants (B=8, S=4096, D=128 per reference setup_inputs)
#define B_ 8
#define S_ 4096
#define D_ 128

typedef __attribute__((ext_vector_type(8))) short bf16x8;   // 8 bf16 = 4 VGPRs (MFMA A/B frag)
typedef __attribute__((ext_vector_type(4))) float f32x4;    // MFMA C/D frag

// f32 -> bf16 round-to-nearest-even
static __device__ __forceinline__ unsigned short f2bf(float x) {
    unsigned u = __float_as_uint(x);
    u += 0x7fffu + ((u >> 16) & 1u);
    return (unsigned short)(u >> 16);
}

// ---------------------------------------------------------------------------
// Kernel 1: apply RoPE to Q and K, convert to bf16.  One thread per (b,s,d).
// emb[d] = s * 10000^{-(d mod 64)/64};  out = x*cos + rot*sin,
// rot[d] = -x[d+64] (d<64) or x[d-64] (d>=64).
// ---------------------------------------------------------------------------
__global__ void rope_qk(const float* __restrict__ Q, const float* __restrict__ K,
                        unsigned short* __restrict__ Qr, unsigned short* __restrict__ Kr) {
    int idx = blockIdx.x * 256 + threadIdx.x;      // 0 .. B*S*D-1
    int d = idx & (D_ - 1);
    int s = (idx >> 7) & (S_ - 1);
    int j = d & 63;
    // inv_freq = 10000^{-j/64} = exp2(-j * log2(10000)/64)
    float invf = exp2f(-0.20762050f * (float)j);
    float ang = (float)s * invf;
    float sn, cs;
    __sincosf(ang, &sn, &cs);
    float q = Q[idx], k = K[idx];
    float qo, ko;
    if (d < 64) { qo = q * cs - Q[idx + 64] * sn;  ko = k * cs - K[idx + 64] * sn; }
    else        { qo = q * cs + Q[idx - 64] * sn;  ko = k * cs + K[idx - 64] * sn; }
    Qr[idx] = f2bf(qo);
    Kr[idx] = f2bf(ko);
}

// ---------------------------------------------------------------------------
// Kernel 2: V [B][S][D] f32  ->  Vt [B][D][S] bf16 (transpose + convert)
// One block per 64(t) x 128(d) tile; LDS stride padded to avoid conflicts.
// ---------------------------------------------------------------------------
__global__ void transpose_v(const float* __restrict__ V, unsigned short* __restrict__ Vt) {
    __shared__ unsigned short tile[64][130];       // 130*2B = 260B stride (65 dwords, odd)
    int b  = blockIdx.x >> 6;                      // 64 tiles per batch
    int t0 = (blockIdx.x & 63) * 64;
    int tid = threadIdx.x;
    #pragma unroll
    for (int it = 0; it < 32; ++it) {              // coalesced f32 reads
        int e = it * 256 + tid;                    // 0..8191
        int tl = e >> 7, d = e & 127;
        tile[tl][d] = f2bf(V[((size_t)(b * S_ + t0 + tl)) * D_ + d]);
    }
    __syncthreads();
    #pragma unroll
    for (int it = 0; it < 32; ++it) {              // coalesced bf16 writes along t
        int e = it * 256 + tid;
        int d = e >> 6, tl = e & 63;
        Vt[((size_t)(b * D_ + d)) * S_ + t0 + tl] = tile[tl][d];
    }
}

// ---------------------------------------------------------------------------
// Kernel 3: causal (no-softmax) attention.
//   Block = 256 threads = 4 waves; each block owns one 64-row Q tile of one batch.
//   Wave w owns 16 Q rows.  K/V fragments read straight from global (L2/L3-resident).
//   E (C-layout) -> P (A-layout) transpose via wave-private swizzled LDS. No barriers.
// MFMA 16x16x32 bf16 layouts (HW-verified):
//   A: lane holds A[row=l&15][k=8*(l>>4)+j]   B: lane holds B[k=8*(l>>4)+j][col=l&15]
//   C/D: lane,reg holds D[row=4*(l>>4)+reg][col=l&15]
// ---------------------------------------------------------------------------
__global__ __launch_bounds__(256) void attn(const unsigned short* __restrict__ Qr,
                                            const unsigned short* __restrict__ Kr,
                                            const unsigned short* __restrict__ Vt,
                                            float* __restrict__ Out) {
    __shared__ unsigned short Plds[4][16 * 64];    // per-wave [16 s][64 t], XOR-swizzled

    const int b  = blockIdx.x & 7;                 // batch
    const int qi = 63 - (blockIdx.x >> 3);         // q-tile index, longest work first
    const int w  = threadIdx.x >> 6;               // wave 0..3
    const int l  = threadIdx.x & 63;
    const int g  = l >> 4;                         // k-group 0..3
    const int n  = l & 15;                         // row/col-within-frag

    // Hoist Q fragments for this wave's 16 rows (s = qi*64 + w*16 + n), all of D.
    bf16x8 qf[4];
    {
        const unsigned short* qp = Qr + ((size_t)(b * S_ + qi * 64 + w * 16 + n)) * D_ + g * 8;
        #pragma unroll
        for (int ks = 0; ks < 4; ++ks)
            qf[ks] = *reinterpret_cast<const bf16x8*>(qp + ks * 32);
    }

    f32x4 o[8];
    #pragma unroll
    for (int i = 0; i < 8; ++i) o[i] = f32x4{0.f, 0.f, 0.f, 0.f};

    unsigned short* pw = &Plds[w][0];

    for (int tt = 0; tt <= qi; ++tt) {
        // ---- E = Q . K^T  (16 s x 64 t), K-frags direct from global ----
        f32x4 e[4];
        #pragma unroll
        for (int tf = 0; tf < 4; ++tf) {
            e[tf] = f32x4{0.f, 0.f, 0.f, 0.f};
            const unsigned short* kp =
                Kr + ((size_t)(b * S_ + tt * 64 + tf * 16 + n)) * D_ + g * 8;
            #pragma unroll
            for (int ks = 0; ks < 4; ++ks) {
                bf16x8 kf = *reinterpret_cast<const bf16x8*>(kp + ks * 32);
                e[tf] = __builtin_amdgcn_mfma_f32_16x16x32_bf16(qf[ks], kf, e[tf], 0, 0, 0);
            }
        }

        // ---- causal mask (only the diagonal tile needs it) ----
        if (tt == qi) {
            #pragma unroll
            for (int tf = 0; tf < 4; ++tf) {
                int t_loc = tf * 16 + n;
                #pragma unroll
                for (int r = 0; r < 4; ++r) {
                    int s_loc = w * 16 + 4 * g + r;
                    if (t_loc > s_loc) e[tf][r] = 0.f;
                }
            }
        }

        // ---- E (C-layout) -> P (A-layout) via wave-private swizzled LDS ----
        // byte(s,t) = (s*128 + 2t) ^ ((s&7)<<4)  — kills stride-128B bank conflict
        #pragma unroll
        for (int tf = 0; tf < 4; ++tf) {
            #pragma unroll
            for (int r = 0; r < 4; ++r) {
                int srow = 4 * g + r;
                int byte = (srow * 128 + (tf * 16 + n) * 2) ^ ((srow & 7) << 4);
                pw[byte >> 1] = f2bf(e[tf][r]);
            }
        }

        bf16x8 pf[2];
        #pragma unroll
        for (int ks = 0; ks < 2; ++ks) {
            int byte = (n * 128 + g * 16 + ks * 64) ^ ((n & 7) << 4);
            pf[ks] = *reinterpret_cast<const bf16x8*>(&pw[byte >> 1]);
        }

        // ---- O += P . V  (V^T rows are contiguous in Vt) ----
        const unsigned short* vp = Vt + ((size_t)(b * D_ + n)) * S_ + tt * 64 + g * 8;
        #pragma unroll
        for (int df = 0; df < 8; ++df) {
            #pragma unroll
            for (int ks = 0; ks < 2; ++ks) {
                bf16x8 vf = *reinterpret_cast<const bf16x8*>(vp + (size_t)df * 16 * S_ + ks * 32);
                o[df] = __builtin_amdgcn_mfma_f32_16x16x32_bf16(pf[ks], vf, o[df], 0, 0, 0);
            }
        }
    }

    // ---- epilogue: fp32 output, C/D layout -> [B][S][D] ----
    #pragma unroll
    for (int df = 0; df < 8; ++df) {
        #pragma unroll
        for (int r = 0; r < 4; ++r) {
            int s = qi * 64 + w * 16 + 4 * g + r;
            Out[((size_t)(b * S_ + s)) * D_ + df * 16 + n] = o[df][r];
        }
    }
}

// ---------------------------------------------------------------------------
extern "C" void kernel_launch(void* const* d_in, const int* in_sizes, int n_in,
                              void* d_out, int out_size, void* d_ws, size_t ws_size,
                              hipStream_t stream) {
    const float* Q = (const float*)d_in[0];
    const float* K = (const float*)d_in[1];
    const float* V = (const float*)d_in[2];

    // workspace: Qr | Kr | Vt  (each B*S*D bf16 = 8 MB, total 24 MB)
    unsigned short* Qr = (unsigned short*)d_ws;
    unsigned short* Kr = Qr + (size_t)B_ * S_ * D_;
    unsigned short* Vt = Kr + (size_t)B_ * S_ * D_;

    rope_qk<<<(B_ * S_ * D_) / 256, 256, 0, stream>>>(Q, K, Qr, Kr);
    transpose_v<<<B_ * (S_ / 64), 256, 0, stream>>>(V, Vt);
    attn<<<B_ * 64, 256, 0, stream>>>(Qr, Kr, Vt, (float*)d_out);
}

// Round 2
// 94.351 us; speedup vs baseline: 4.0967x; 4.0967x over previous
//
#include <hip/hip_runtime.h>
#include <hip/hip_bf16.h>

// Problem constants (B=8, S=4096, D=128 per reference setup_inputs)
#define B_ 8
#define S_ 4096
#define D_ 128

typedef __attribute__((ext_vector_type(8))) short bf16x8;   // 8 bf16 = 4 VGPRs (MFMA A/B frag)
typedef __attribute__((ext_vector_type(4))) float f32x4;    // MFMA C/D frag

// f32 -> bf16 round-to-nearest-even
static __device__ __forceinline__ unsigned short f2bf(float x) {
    unsigned u = __float_as_uint(x);
    u += 0x7fffu + ((u >> 16) & 1u);
    return (unsigned short)(u >> 16);
}

// async global -> LDS, 16 bytes per lane (dest = wave-uniform base + lane*16)
typedef const __attribute__((address_space(1))) unsigned int* gas_ptr;
typedef __attribute__((address_space(3))) unsigned int* las_ptr;
static __device__ __forceinline__ void load_lds16(const unsigned short* g, unsigned short* l) {
    __builtin_amdgcn_global_load_lds((gas_ptr)(const void*)g, (las_ptr)(void*)l, 16, 0, 0);
}

// ---------------------------------------------------------------------------
// Kernel 0: zero d_out (both split-K halves atomicAdd into it)
// ---------------------------------------------------------------------------
__global__ void zero_out(float4* __restrict__ o) {
    o[blockIdx.x * 256 + threadIdx.x] = float4{0.f, 0.f, 0.f, 0.f};
}

// ---------------------------------------------------------------------------
// Kernel 1: RoPE Q,K -> bf16
// ---------------------------------------------------------------------------
__global__ void rope_qk(const float* __restrict__ Q, const float* __restrict__ K,
                        unsigned short* __restrict__ Qr, unsigned short* __restrict__ Kr) {
    int idx = blockIdx.x * 256 + threadIdx.x;
    int d = idx & (D_ - 1);
    int s = (idx >> 7) & (S_ - 1);
    int j = d & 63;
    float invf = exp2f(-0.20762050f * (float)j);     // 10000^{-j/64}
    float ang = (float)s * invf;
    float sn, cs;
    __sincosf(ang, &sn, &cs);
    float q = Q[idx], k = K[idx];
    float qo, ko;
    if (d < 64) { qo = q * cs - Q[idx + 64] * sn;  ko = k * cs - K[idx + 64] * sn; }
    else        { qo = q * cs + Q[idx - 64] * sn;  ko = k * cs + K[idx - 64] * sn; }
    Qr[idx] = f2bf(qo);
    Kr[idx] = f2bf(ko);
}

// ---------------------------------------------------------------------------
// Kernel 2: V [B][S][D] f32 -> Vt [B][D][S] bf16
// ---------------------------------------------------------------------------
__global__ void transpose_v(const float* __restrict__ V, unsigned short* __restrict__ Vt) {
    __shared__ unsigned short tile[64][130];
    int b  = blockIdx.x >> 6;
    int t0 = (blockIdx.x & 63) * 64;
    int tid = threadIdx.x;
    #pragma unroll
    for (int it = 0; it < 32; ++it) {
        int e = it * 256 + tid;
        int tl = e >> 7, d = e & 127;
        tile[tl][d] = f2bf(V[((size_t)(b * S_ + t0 + tl)) * D_ + d]);
    }
    __syncthreads();
    #pragma unroll
    for (int it = 0; it < 32; ++it) {
        int e = it * 256 + tid;
        int d = e >> 6, tl = e & 63;
        Vt[((size_t)(b * D_ + d)) * S_ + t0 + tl] = tile[tl][d];
    }
}

// ---------------------------------------------------------------------------
// Kernel 3: causal no-softmax attention, split-K 2-way.
//   Block = 4 waves, BM=128 q-rows (32 rows/wave as 2 row-groups), BN=64.
//   K/V tiles double-buffered in LDS via global_load_lds with pre-swizzled
//   global source (linear LDS dest) + XOR-swizzled ds_read_b128 frag reads.
//   Block r: qi = 31-(r>>4), half=(r>>3)&1, b=r&7;
//   lo half: kt in [0,qi+1), hi half: kt in [qi+1,2qi+2). atomicAdd epilogue.
// MFMA 16x16x32 bf16 layouts (verified round 1):
//   A: lane l holds A[row=l&15][k=8*(l>>4)+j]; B: B[k=8*(l>>4)+j][col=l&15]
//   C/D: lane,reg holds D[row=4*(l>>4)+reg][col=l&15]
// ---------------------------------------------------------------------------
__global__ __launch_bounds__(256, 2) void attn(const unsigned short* __restrict__ Qr,
                                               const unsigned short* __restrict__ Kr,
                                               const unsigned short* __restrict__ Vt,
                                               float* __restrict__ Out) {
    __shared__ unsigned short Kb[2][64 * 128];   // [t][d], K-swizzled chunks, 2x16KB
    __shared__ unsigned short Vb[2][128 * 64];   // [d][t], V-swizzled chunks, 2x16KB
    __shared__ unsigned short Pb[4][32 * 64];    // per-wave P [s][t], 4x4KB

    const int r    = blockIdx.x;
    const int qi   = 31 - (r >> 4);              // longest work dispatched first
    const int half = (r >> 3) & 1;
    const int b    = r & 7;
    const int kt0  = half ? (qi + 1) : 0;
    const int kt1  = half ? (2 * qi + 2) : (qi + 1);

    const int tid = threadIdx.x;
    const int w = tid >> 6;                      // wave 0..3
    const int l = tid & 63;
    const int g = l >> 4;                        // lane k-group 0..3
    const int n = l & 15;                        // frag row/col

    // ---- hoist Q fragments: wave w owns q-rows [w*32, w*32+32) of the tile ----
    bf16x8 qf[2][4];
    #pragma unroll
    for (int rg = 0; rg < 2; ++rg) {
        const unsigned short* qp =
            Qr + ((size_t)(b * S_ + qi * 128 + w * 32 + rg * 16 + n)) * D_ + 8 * g;
        #pragma unroll
        for (int ks = 0; ks < 4; ++ks)
            qf[rg][ks] = *reinterpret_cast<const bf16x8*>(qp + ks * 32);
    }

    f32x4 o[2][8];
    #pragma unroll
    for (int rg = 0; rg < 2; ++rg)
        #pragma unroll
        for (int df = 0; df < 8; ++df) o[rg][df] = f32x4{0.f, 0.f, 0.f, 0.f};

    // ---- staging: K tile 1024 16B-chunks, V tile 1024 16B-chunks ----
    // K LDS chunk (t, c) holds global chunk (t, c^(t&15));  c = byte/16 in 256B row
    // V LDS chunk (d, c) holds global chunk (d, c^(d&7));   c = byte/16 in 128B row
    auto stage = [&](int buf, int kt) {
        const unsigned short* kbase = Kr + ((size_t)(b * S_ + kt * 64)) * D_;
        #pragma unroll
        for (int i = 0; i < 4; ++i) {
            int ci = i * 256 + tid;
            int t = ci >> 4, c = ci & 15;
            load_lds16(kbase + t * D_ + ((c ^ (t & 15)) * 8), &Kb[buf][ci * 8]);
        }
        const unsigned short* vbase = Vt + (size_t)b * D_ * S_ + kt * 64;
        #pragma unroll
        for (int i = 0; i < 4; ++i) {
            int ci = i * 256 + tid;
            int d = ci >> 3, c = ci & 7;
            load_lds16(vbase + (size_t)d * S_ + ((c ^ (d & 7)) * 8), &Vb[buf][ci * 8]);
        }
    };

    stage(0, kt0);
    __syncthreads();

    unsigned short* pw = &Pb[w][0];
    int buf = 0;

    for (int kt = kt0; kt < kt1; ++kt) {
        if (kt + 1 < kt1) stage(buf ^ 1, kt + 1);

        // ---- E = Q.K^T (32 s x 64 t per wave) ----
        f32x4 e[2][4];
        #pragma unroll
        for (int rg = 0; rg < 2; ++rg)
            #pragma unroll
            for (int tf = 0; tf < 4; ++tf) e[rg][tf] = f32x4{0.f, 0.f, 0.f, 0.f};
        #pragma unroll
        for (int tf = 0; tf < 4; ++tf) {
            #pragma unroll
            for (int ks = 0; ks < 4; ++ks) {
                // frag row t = tf*16+n (t&15 == n), chunk c = 4ks+g, read at c^n
                const bf16x8 kf = *reinterpret_cast<const bf16x8*>(
                    &Kb[buf][(tf * 16 + n) * 128 + (((4 * ks + g) ^ n) * 8)]);
                e[0][tf] = __builtin_amdgcn_mfma_f32_16x16x32_bf16(qf[0][ks], kf, e[0][tf], 0, 0, 0);
                e[1][tf] = __builtin_amdgcn_mfma_f32_16x16x32_bf16(qf[1][ks], kf, e[1][tf], 0, 0, 0);
            }
        }

        // ---- causal mask (only the two diagonal-straddling tiles) ----
        if (kt >= 2 * qi) {
            #pragma unroll
            for (int rg = 0; rg < 2; ++rg)
                #pragma unroll
                for (int tf = 0; tf < 4; ++tf) {
                    int t_glob = kt * 64 + tf * 16 + n;
                    #pragma unroll
                    for (int rr = 0; rr < 4; ++rr) {
                        int s_glob = qi * 128 + w * 32 + rg * 16 + 4 * g + rr;
                        if (t_glob > s_glob) e[rg][tf][rr] = 0.f;
                    }
                }
        }

        // ---- E (C-layout) -> P (A-layout), wave-private swizzled LDS ----
        #pragma unroll
        for (int rg = 0; rg < 2; ++rg)
            #pragma unroll
            for (int tf = 0; tf < 4; ++tf)
                #pragma unroll
                for (int rr = 0; rr < 4; ++rr) {
                    int sl = rg * 16 + 4 * g + rr;
                    int byte = (sl * 128 + (tf * 16 + n) * 2) ^ ((sl & 7) << 4);
                    pw[byte >> 1] = f2bf(e[rg][tf][rr]);
                }

        bf16x8 pf[2][2];
        #pragma unroll
        for (int rg = 0; rg < 2; ++rg)
            #pragma unroll
            for (int ks = 0; ks < 2; ++ks) {
                int sl = rg * 16 + n;
                int byte = (sl * 128 + ks * 64 + g * 16) ^ ((sl & 7) << 4);
                pf[rg][ks] = *reinterpret_cast<const bf16x8*>(&pw[byte >> 1]);
            }

        // ---- O += P.V ----
        #pragma unroll
        for (int df = 0; df < 8; ++df) {
            #pragma unroll
            for (int ks = 0; ks < 2; ++ks) {
                // frag row d = df*16+n, chunk c = 4ks+g, read at c^(d&7)=c^(n&7)
                const bf16x8 vf = *reinterpret_cast<const bf16x8*>(
                    &Vb[buf][(df * 16 + n) * 64 + (((4 * ks + g) ^ (n & 7)) * 8)]);
                o[0][df] = __builtin_amdgcn_mfma_f32_16x16x32_bf16(pf[0][ks], vf, o[0][df], 0, 0, 0);
                o[1][df] = __builtin_amdgcn_mfma_f32_16x16x32_bf16(pf[1][ks], vf, o[1][df], 0, 0, 0);
            }
        }

        __syncthreads();          // drains vmcnt -> next buf staged & visible
        buf ^= 1;
    }

    // ---- epilogue: accumulate into pre-zeroed output ----
    #pragma unroll
    for (int rg = 0; rg < 2; ++rg)
        #pragma unroll
        for (int df = 0; df < 8; ++df)
            #pragma unroll
            for (int rr = 0; rr < 4; ++rr) {
                int srow = qi * 128 + w * 32 + rg * 16 + 4 * g + rr;
                atomicAdd(&Out[((size_t)(b * S_ + srow)) * D_ + df * 16 + n], o[rg][df][rr]);
            }
}

// ---------------------------------------------------------------------------
extern "C" void kernel_launch(void* const* d_in, const int* in_sizes, int n_in,
                              void* d_out, int out_size, void* d_ws, size_t ws_size,
                              hipStream_t stream) {
    const float* Q = (const float*)d_in[0];
    const float* K = (const float*)d_in[1];
    const float* V = (const float*)d_in[2];

    unsigned short* Qr = (unsigned short*)d_ws;
    unsigned short* Kr = Qr + (size_t)B_ * S_ * D_;
    unsigned short* Vt = Kr + (size_t)B_ * S_ * D_;

    zero_out<<<(B_ * S_ * D_) / (256 * 4), 256, 0, stream>>>((float4*)d_out);
    rope_qk<<<(B_ * S_ * D_) / 256, 256, 0, stream>>>(Q, K, Qr, Kr);
    transpose_v<<<B_ * (S_ / 64), 256, 0, stream>>>(V, Vt);
    attn<<<512, 256, 0, stream>>>(Qr, Kr, Vt, (float*)d_out);
}

// Round 3
// 78.137 us; speedup vs baseline: 4.9469x; 1.2075x over previous
//
#include <hip/hip_runtime.h>
#include <hip/hip_bf16.h>

// Problem constants (B=8, S=4096, D=128 per reference setup_inputs)
#define B_ 8
#define S_ 4096
#define D_ 128
#define NQT 32            // q-tiles per batch (BM=128)
#define WPB 1056          // work items per batch = NQT*(NQT+1)

typedef __attribute__((ext_vector_type(8))) short bf16x8;   // MFMA A/B frag (4 VGPRs)
typedef __attribute__((ext_vector_type(4))) float f32x4;    // MFMA C/D frag

// f32 -> bf16 round-to-nearest-even
static __device__ __forceinline__ unsigned short f2bf(float x) {
    unsigned u = __float_as_uint(x);
    u += 0x7fffu + ((u >> 16) & 1u);
    return (unsigned short)(u >> 16);
}

// async global -> LDS, 16 bytes per lane (dest = wave-uniform base + lane*16)
typedef const __attribute__((address_space(1))) unsigned int* gas_ptr;
typedef __attribute__((address_space(3))) unsigned int* las_ptr;
static __device__ __forceinline__ void load_lds16(const unsigned short* g, unsigned short* l) {
    __builtin_amdgcn_global_load_lds((gas_ptr)(const void*)g, (las_ptr)(void*)l, 16, 0, 0);
}

// ---------------------------------------------------------------------------
// Fused prep kernel: [0,2048) RoPE Q,K -> bf16 (vectorized, d/d+64 paired)
//                    [2048,6144) zero d_out ; [6144,6656) V transpose -> bf16
// ---------------------------------------------------------------------------
__global__ __launch_bounds__(256) void prep(const float* __restrict__ Q,
                                            const float* __restrict__ K,
                                            const float* __restrict__ V,
                                            unsigned short* __restrict__ Qr,
                                            unsigned short* __restrict__ Kr,
                                            unsigned short* __restrict__ Vt,
                                            float4* __restrict__ Oz) {
    __shared__ unsigned short tile[64][130];
    const int bid = blockIdx.x;
    if (bid < 2048) {
        // ---- RoPE: each thread: 4 (d, d+64) pairs, float4 loads, ushort4 stores
        int e = bid * 256 + threadIdx.x;          // 0 .. 8*4096*16-1
        int t = e & 15;
        int s = (e >> 4) & (S_ - 1);
        int b = e >> 16;
        size_t base = ((size_t)(b * S_ + s)) * D_;
        int d0 = t * 4;
        float qa[4], qb[4], ka[4], kb[4];
        *(float4*)qa = *(const float4*)(Q + base + d0);
        *(float4*)qb = *(const float4*)(Q + base + d0 + 64);
        *(float4*)ka = *(const float4*)(K + base + d0);
        *(float4*)kb = *(const float4*)(K + base + d0 + 64);
        unsigned short ql[4], qh[4], kl[4], kh[4];
        #pragma unroll
        for (int j = 0; j < 4; ++j) {
            float invf = exp2f(-0.20762050f * (float)(d0 + j));   // 10000^{-(d0+j)/64}
            float ang = (float)s * invf;
            float sn, cs;
            __sincosf(ang, &sn, &cs);
            ql[j] = f2bf(qa[j] * cs - qb[j] * sn);
            qh[j] = f2bf(qb[j] * cs + qa[j] * sn);
            kl[j] = f2bf(ka[j] * cs - kb[j] * sn);
            kh[j] = f2bf(kb[j] * cs + ka[j] * sn);
        }
        *reinterpret_cast<ushort4*>(Qr + base + d0)      = ushort4{ql[0], ql[1], ql[2], ql[3]};
        *reinterpret_cast<ushort4*>(Qr + base + d0 + 64) = ushort4{qh[0], qh[1], qh[2], qh[3]};
        *reinterpret_cast<ushort4*>(Kr + base + d0)      = ushort4{kl[0], kl[1], kl[2], kl[3]};
        *reinterpret_cast<ushort4*>(Kr + base + d0 + 64) = ushort4{kh[0], kh[1], kh[2], kh[3]};
    } else if (bid < 6144) {
        // ---- zero d_out (atomicAdd target)
        Oz[(size_t)(bid - 2048) * 256 + threadIdx.x] = float4{0.f, 0.f, 0.f, 0.f};
    } else {
        // ---- V [B][S][D] f32 -> Vt [B][D][S] bf16
        int b2 = bid - 6144;                      // 0..511
        int b  = b2 >> 6;
        int t0 = (b2 & 63) * 64;
        int tid = threadIdx.x;
        #pragma unroll
        for (int it = 0; it < 32; ++it) {
            int e = it * 256 + tid;
            int tl = e >> 7, d = e & 127;
            tile[tl][d] = f2bf(V[((size_t)(b * S_ + t0 + tl)) * D_ + d]);
        }
        __syncthreads();
        #pragma unroll
        for (int it = 0; it < 32; ++it) {
            int e = it * 256 + tid;
            int d = e >> 6, tl = e & 63;
            Vt[((size_t)(b * D_ + d)) * S_ + t0 + tl] = tile[tl][d];
        }
    }
}

// ---------------------------------------------------------------------------
// Causal no-softmax attention, stream-K balanced.
//   Per batch: work items w in [0,1056) = flattened (qi, kt): q-tile qi owns
//   [qi*(qi+1), (qi+1)*(qi+2)), kt = w - qi*(qi+1) in [0, 2qi+2).
//   512 blocks = 8 batches x 64 equal chunks of 16-17 items; K/V staging is a
//   pure kt-stream (independent of qi) -> seamless double buffering. Flush O
//   (atomicAdd) + rehoist Q at q-tile crossings.
//   Swapped E = mfma(K,Q): lane holds 4 consecutive t -> packed b64 P-writes.
// MFMA 16x16x32 bf16 layouts (verified rounds 1-2):
//   A: lane l holds A[row=l&15][k=8*(l>>4)+j]; B: B[k=8*(l>>4)+j][col=l&15]
//   C/D: lane,reg holds D[row=4*(l>>4)+reg][col=l&15]
// ---------------------------------------------------------------------------
__global__ __launch_bounds__(256, 2) void attn(const unsigned short* __restrict__ Qr,
                                               const unsigned short* __restrict__ Kr,
                                               const unsigned short* __restrict__ Vt,
                                               float* __restrict__ Out) {
    __shared__ unsigned short Kb[2][64 * 128];   // [t][d] swizzled chunks, 2x16KB
    __shared__ unsigned short Vb[2][128 * 64];   // [d][t] swizzled chunks, 2x16KB
    __shared__ unsigned short Pb[4][32 * 64];    // per-wave P [s][t] swizzled, 4x4KB

    const int r  = blockIdx.x;
    const int b  = r & 7;
    const int j  = r >> 3;                        // chunk 0..63 within batch
    const int w0 = (j * 33) >> 1;                 // chunk = [w0, w1), 16 or 17 items
    const int w1 = ((j + 1) * 33) >> 1;

    int qi = 0;
    while ((qi + 1) * (qi + 2) <= w0) ++qi;       // q-tile containing w0
    int kt = w0 - qi * (qi + 1);

    const int tid = threadIdx.x;
    const int wv = tid >> 6;                      // wave 0..3
    const int l  = tid & 63;
    const int g  = l >> 4;                        // k-group 0..3
    const int n  = l & 15;                        // frag row/col

    bf16x8 qf[2][4];
    auto hoistQ = [&](int qq) {
        #pragma unroll
        for (int rg = 0; rg < 2; ++rg) {
            const unsigned short* qp =
                Qr + ((size_t)(b * S_ + qq * 128 + wv * 32 + rg * 16 + n)) * D_ + 8 * g;
            #pragma unroll
            for (int ks = 0; ks < 4; ++ks)
                qf[rg][ks] = *reinterpret_cast<const bf16x8*>(qp + ks * 32);
        }
    };

    f32x4 o[2][8];
    auto zeroO = [&]() {
        #pragma unroll
        for (int rg = 0; rg < 2; ++rg)
            #pragma unroll
            for (int df = 0; df < 8; ++df) o[rg][df] = f32x4{0.f, 0.f, 0.f, 0.f};
    };
    auto flush = [&](int qq) {
        #pragma unroll
        for (int rg = 0; rg < 2; ++rg)
            #pragma unroll
            for (int df = 0; df < 8; ++df)
                #pragma unroll
                for (int rr = 0; rr < 4; ++rr) {
                    int srow = qq * 128 + wv * 32 + rg * 16 + 4 * g + rr;
                    atomicAdd(&Out[((size_t)(b * S_ + srow)) * D_ + df * 16 + n],
                              o[rg][df][rr]);
                }
    };

    // K LDS chunk (t,c) holds global chunk (t, c^(t&15)); V chunk (d,c): c^(d&7)
    auto stage = [&](int buf, int ktg) {
        const unsigned short* kbase = Kr + ((size_t)(b * S_ + ktg * 64)) * D_;
        #pragma unroll
        for (int i = 0; i < 4; ++i) {
            int ci = i * 256 + tid;
            int t = ci >> 4, c = ci & 15;
            load_lds16(kbase + t * D_ + ((c ^ (t & 15)) * 8), &Kb[buf][ci * 8]);
        }
        const unsigned short* vbase = Vt + (size_t)b * D_ * S_ + ktg * 64;
        #pragma unroll
        for (int i = 0; i < 4; ++i) {
            int ci = i * 256 + tid;
            int d = ci >> 3, c = ci & 7;
            load_lds16(vbase + (size_t)d * S_ + ((c ^ (d & 7)) * 8), &Vb[buf][ci * 8]);
        }
    };

    hoistQ(qi);
    zeroO();
    stage(0, kt);
    __syncthreads();

    unsigned short* pw = &Pb[wv][0];
    int buf = 0;

    for (int w = w0; w < w1; ++w) {
        if (w + 1 < w1) {
            int nkt = kt + 1;
            stage(buf ^ 1, (nkt == 2 * qi + 2) ? 0 : nkt);
        }

        // ---- E^T = K.Q^T (swapped): D[row=t][col=s], lane holds 4 consecutive t
        f32x4 e[2][4];
        #pragma unroll
        for (int rg = 0; rg < 2; ++rg)
            #pragma unroll
            for (int tf = 0; tf < 4; ++tf) e[rg][tf] = f32x4{0.f, 0.f, 0.f, 0.f};
        __builtin_amdgcn_s_setprio(1);
        #pragma unroll
        for (int tf = 0; tf < 4; ++tf) {
            #pragma unroll
            for (int ks = 0; ks < 4; ++ks) {
                const bf16x8 kf = *reinterpret_cast<const bf16x8*>(
                    &Kb[buf][(tf * 16 + n) * 128 + (((4 * ks + g) ^ n) * 8)]);
                e[0][tf] = __builtin_amdgcn_mfma_f32_16x16x32_bf16(kf, qf[0][ks], e[0][tf], 0, 0, 0);
                e[1][tf] = __builtin_amdgcn_mfma_f32_16x16x32_bf16(kf, qf[1][ks], e[1][tf], 0, 0, 0);
            }
        }
        __builtin_amdgcn_s_setprio(0);

        // ---- causal mask (diagonal-straddling tiles: kt in {2qi, 2qi+1})
        if (kt >= 2 * qi) {
            #pragma unroll
            for (int rg = 0; rg < 2; ++rg)
                #pragma unroll
                for (int tf = 0; tf < 4; ++tf) {
                    int s_glob = qi * 128 + wv * 32 + rg * 16 + n;
                    #pragma unroll
                    for (int rr = 0; rr < 4; ++rr) {
                        int t_glob = kt * 64 + tf * 16 + 4 * g + rr;
                        if (t_glob > s_glob) e[rg][tf][rr] = 0.f;
                    }
                }
        }

        // ---- pack 4 consecutive t -> 2 u32 (cvt_pk) -> one ds_write_b64 each
        #pragma unroll
        for (int rg = 0; rg < 2; ++rg)
            #pragma unroll
            for (int tf = 0; tf < 4; ++tf) {
                unsigned lo, hi;
                asm("v_cvt_pk_bf16_f32 %0, %1, %2"
                    : "=v"(lo) : "v"(e[rg][tf][0]), "v"(e[rg][tf][1]));
                asm("v_cvt_pk_bf16_f32 %0, %1, %2"
                    : "=v"(hi) : "v"(e[rg][tf][2]), "v"(e[rg][tf][3]));
                int sl = rg * 16 + n;
                int byte = (sl * 128 + tf * 32 + 8 * g) ^ ((sl & 7) << 4);
                *reinterpret_cast<uint2*>(reinterpret_cast<char*>(pw) + byte) = uint2{lo, hi};
            }

        // ---- P A-frags (same swizzle), then O += P.V
        bf16x8 pf[2][2];
        #pragma unroll
        for (int rg = 0; rg < 2; ++rg)
            #pragma unroll
            for (int ks = 0; ks < 2; ++ks) {
                int sl = rg * 16 + n;
                int byte = (sl * 128 + ks * 64 + g * 16) ^ ((sl & 7) << 4);
                pf[rg][ks] = *reinterpret_cast<const bf16x8*>(
                    reinterpret_cast<char*>(pw) + byte);
            }

        __builtin_amdgcn_s_setprio(1);
        #pragma unroll
        for (int df = 0; df < 8; ++df) {
            #pragma unroll
            for (int ks = 0; ks < 2; ++ks) {
                const bf16x8 vf = *reinterpret_cast<const bf16x8*>(
                    &Vb[buf][(df * 16 + n) * 64 + (((4 * ks + g) ^ (n & 7)) * 8)]);
                o[0][df] = __builtin_amdgcn_mfma_f32_16x16x32_bf16(pf[0][ks], vf, o[0][df], 0, 0, 0);
                o[1][df] = __builtin_amdgcn_mfma_f32_16x16x32_bf16(pf[1][ks], vf, o[1][df], 0, 0, 0);
            }
        }
        __builtin_amdgcn_s_setprio(0);

        __syncthreads();          // drains vmcnt -> next buf staged & visible
        buf ^= 1;

        ++kt;
        if (kt == 2 * qi + 2 && w + 1 < w1) {     // q-tile crossing mid-chunk
            flush(qi);
            zeroO();
            ++qi;
            kt = 0;
            hoistQ(qi);
        }
    }
    flush(qi);
}

// ---------------------------------------------------------------------------
extern "C" void kernel_launch(void* const* d_in, const int* in_sizes, int n_in,
                              void* d_out, int out_size, void* d_ws, size_t ws_size,
                              hipStream_t stream) {
    const float* Q = (const float*)d_in[0];
    const float* K = (const float*)d_in[1];
    const float* V = (const float*)d_in[2];

    unsigned short* Qr = (unsigned short*)d_ws;
    unsigned short* Kr = Qr + (size_t)B_ * S_ * D_;
    unsigned short* Vt = Kr + (size_t)B_ * S_ * D_;

    prep<<<6656, 256, 0, stream>>>(Q, K, V, Qr, Kr, Vt, (float4*)d_out);
    attn<<<512, 256, 0, stream>>>(Qr, Kr, Vt, (float*)d_out);
}